// Round 2
// baseline (383.446 us; speedup 1.0000x reference)
//
#include <hip/hip_runtime.h>

// MaxMin pooling: in [C, H] fp32, windows of 4 along H.
// out[c, 2i]   = argmax(window) as float (first-occurrence ties, strict >)
// out[c, 2i+1] = min(window)
//
// R1: 2 windows per thread. Reads: 2x float4 (32 B/lane, 2 loads in flight).
// Store: 1x float4 (16 B/lane sweet spot; matches the 6.6 TB/s fill kernels'
// access pattern). Memory-bound: 256 MiB read + 128 MiB write -> ~62 us floor
// at the measured 6.6 TB/s streaming ceiling.

__device__ __forceinline__ float2 window_maxmin(float4 w)
{
    float m   = w.x;
    float idx = 0.0f;
    if (w.y > m) { m = w.y; idx = 1.0f; }
    if (w.z > m) { m = w.z; idx = 2.0f; }
    if (w.w > m) { m = w.w; idx = 3.0f; }
    float mn = fminf(fminf(w.x, w.y), fminf(w.z, w.w));
    return make_float2(idx, mn);
}

__global__ __launch_bounds__(256) void maxmin_kernel(
    const float4* __restrict__ in, float4* __restrict__ out, int npair)
{
    int i = blockIdx.x * blockDim.x + threadIdx.x;
    if (i >= npair) return;

    // two adjacent windows -> 32 contiguous bytes per lane
    float4 a = in[2 * i];
    float4 b = in[2 * i + 1];

    float2 ra = window_maxmin(a);
    float2 rb = window_maxmin(b);

    out[i] = make_float4(ra.x, ra.y, rb.x, rb.y);
}

extern "C" void kernel_launch(void* const* d_in, const int* in_sizes, int n_in,
                              void* d_out, int out_size, void* d_ws, size_t ws_size,
                              hipStream_t stream)
{
    const float* in = (const float*)d_in[0];
    float* out = (float*)d_out;

    int nwin_total = in_sizes[0] / 4;       // 16,777,216 windows
    int npair = nwin_total / 2;             // 8,388,608 thread work-items
    int block = 256;
    int grid = (npair + block - 1) / block; // 32768 blocks

    maxmin_kernel<<<grid, block, 0, stream>>>(
        (const float4*)in, (float4*)out, npair);
}